// Round 1
// baseline (303.177 us; speedup 1.0000x reference)
//
#include <hip/hip_runtime.h>

#define QD 512
#define KD 64
#define LDT 68   // t/o tile row stride in floats (64 + 4 pad); 272 B, 16B-aligned
#define LDU 72   // u tile row stride in shorts (64 + 8 pad); 144 B, 16B-aligned

typedef __attribute__((ext_vector_type(8))) short short8;
typedef __attribute__((ext_vector_type(4))) float f32x4;

static __device__ __forceinline__ unsigned short f2bf(float f) {
  unsigned u = __builtin_bit_cast(unsigned, f);
  u += 0x7FFFu + ((u >> 16) & 1u);   // round-to-nearest-even
  return (unsigned short)(u >> 16);
}
static __device__ __forceinline__ float bf2f(unsigned short s) {
  return __builtin_bit_cast(float, (unsigned)s << 16);
}
static __device__ __forceinline__ short8 pack8(f32x4 a, f32x4 b) {
  short8 r;
  r[0] = (short)f2bf(a[0]); r[1] = (short)f2bf(a[1]);
  r[2] = (short)f2bf(a[2]); r[3] = (short)f2bf(a[3]);
  r[4] = (short)f2bf(b[0]); r[5] = (short)f2bf(b[1]);
  r[6] = (short)f2bf(b[2]); r[7] = (short)f2bf(b[3]);
  return r;
}

// wave-local LDS handoff: drain DS ops; "memory" clobber stops the compiler
// from moving any memory op across. No __syncthreads anywhere in the hot path.
#define WAVE_LDS_FENCE() asm volatile("s_waitcnt lgkmcnt(0)" ::: "memory")

// Prep: M^T[c][d] = sum_e w_q[e,d]*w_k[e,c]  (bf16), plus w_v cast to bf16.
__global__ __launch_bounds__(256) void prep_kernel(
    const float* __restrict__ w_q, const float* __restrict__ w_k,
    const float* __restrict__ w_v, unsigned short* __restrict__ mt,
    unsigned short* __restrict__ wvb) {
  const int tid = (int)(blockIdx.x * 256 + threadIdx.x);
  if (tid < QD * KD) {
    const int c = tid >> 9;      // 0..63
    const int d = tid & 511;     // 0..511
    float acc = 0.f;
#pragma unroll 8
    for (int e = 0; e < 64; ++e)
      acc = fmaf(w_q[e * QD + d], w_k[e * KD + c], acc);
    mt[c * QD + d] = f2bf(acc);
  } else {
    const int i = tid - QD * KD;
    if (i < KD * KD) wvb[i] = f2bf(w_v[i]);
  }
}

// Wave-independent fused kernel: each wave owns 16 rows end-to-end.
// GEMM1 A-frags come straight from global (A-frag layout = 8 consecutive
// floats per lane), B-frags (M^T) from L2-resident global. All transposes
// are wave-local LDS round-trips fenced by lgkmcnt(0) — zero barriers, so
// waves slip freely and keep HBM loads in flight.
// NOTE: no min-waves clause on __launch_bounds__ (round-2/3 evidence: (256,6)
// collapsed to 40 VGPRs and spilled ~40 MB to scratch).
__global__ __launch_bounds__(256) void fused_kernel(
    const float* __restrict__ query,
    const float* __restrict__ kv,
    const unsigned short* __restrict__ mt,
    const unsigned short* __restrict__ wvb,
    const float* __restrict__ gamma,
    const float* __restrict__ beta,
    float* __restrict__ out) {
  // per-wave private tiles: t/o 16x68 f32 (4352 B) + u 16x72 bf16 (2304 B)
  __shared__ __align__(16) float lds_t_all[4][16 * LDT];
  __shared__ __align__(16) unsigned short lds_u_all[4][16 * LDU];

  const int tid  = (int)threadIdx.x;
  const int w    = tid >> 6;       // wave 0..3
  const int l    = tid & 63;
  const int m    = l & 15;
  const int quad = l >> 4;

  float* lds_t = lds_t_all[w];
  unsigned short* lds_u = lds_u_all[w];

  const long row0 = ((long)blockIdx.x * 4 + w) * 16;   // 16 rows per wave

  // ---- GEMM1: t[16][64] = q_tile[16][512] @ M[512][64] ----
  // A-frag: lane reads query[row0+m][ks*32 + quad*8 .. +8] (32 B fp32).
  // B-frag ct: lane reads mt[(ct*16+m)][ks*32 + quad*8 .. +8] (16 B bf16, L2).
  const float* qbase = query + (row0 + m) * QD + quad * 8;
  const unsigned short* mbase = mt + m * QD + quad * 8;

  f32x4 acc[4];
#pragma unroll
  for (int ct = 0; ct < 4; ++ct) acc[ct] = (f32x4){0.f, 0.f, 0.f, 0.f};

  // depth-2 prefetch on query (HBM latency), depth-1 on M^T (L2 latency)
  f32x4 q0 = ((const f32x4*)qbase)[0];
  f32x4 q1 = ((const f32x4*)qbase)[1];
  f32x4 p0 = ((const f32x4*)(qbase + 32))[0];
  f32x4 p1 = ((const f32x4*)(qbase + 32))[1];
  short8 bc[4], bn[4];
#pragma unroll
  for (int ct = 0; ct < 4; ++ct)
    bc[ct] = *(const short8*)(mbase + ct * 16 * QD);

#pragma unroll
  for (int ks = 0; ks < 16; ++ks) {
    short8 af = pack8(q0, q1);
    if (ks < 15) {
#pragma unroll
      for (int ct = 0; ct < 4; ++ct)
        bn[ct] = *(const short8*)(mbase + ct * 16 * QD + (ks + 1) * 32);
    }
    q0 = p0; q1 = p1;
    if (ks < 14) {
      const float* np = qbase + (ks + 2) * 32;
      p0 = ((const f32x4*)np)[0];
      p1 = ((const f32x4*)np)[1];
    }
#pragma unroll
    for (int ct = 0; ct < 4; ++ct)
      acc[ct] = __builtin_amdgcn_mfma_f32_16x16x32_bf16(af, bc[ct], acc[ct], 0, 0, 0);
#pragma unroll
    for (int ct = 0; ct < 4; ++ct) bc[ct] = bn[ct];   // dead at ks==15, DCE'd
  }

  // ---- t -> LDS (C layout: col = ct*16+m, row = quad*4+r), wave-local ----
#pragma unroll
  for (int ct = 0; ct < 4; ++ct)
#pragma unroll
    for (int r = 0; r < 4; ++r)
      lds_t[(quad * 4 + r) * LDT + ct * 16 + m] = acc[ct][r];
  WAVE_LDS_FENCE();

  // ---- attention: 8 lanes/row, 16 rows in 2 passes of 8 ----
  const int rseg = l >> 3;    // 0..7: row within pass
  const int o8   = l & 7;     // dim segment
  const int db   = o8 * 8;

  // hoist gamma/beta (L2)
  f32x4 g0 = ((const f32x4*)(gamma + db))[0];
  f32x4 g1 = ((const f32x4*)(gamma + db))[1];
  f32x4 e0 = ((const f32x4*)(beta + db))[0];
  f32x4 e1 = ((const f32x4*)(beta + db))[1];

#pragma unroll
  for (int p = 0; p < 2; ++p) {
    const int rl = p * 8 + rseg;
    const long brow = row0 + rl;
    const float* tp = lds_t + rl * LDT + db;
    f32x4 tv0 = ((const f32x4*)tp)[0];
    f32x4 tv1 = ((const f32x4*)tp)[1];

    float s[8];
    short8 kvb[8];
#pragma unroll
    for (int n = 0; n < 8; ++n) {   // 16 independent dwordx4 -> 256 B in flight
      const float* kp = kv + (brow * 8 + n) * 64 + db;
      f32x4 k0 = ((const f32x4*)kp)[0];
      f32x4 k1 = ((const f32x4*)kp)[1];
      f32x4 d = tv0 * k0 + tv1 * k1;
      s[n] = d[0] + d[1] + d[2] + d[3];
      kvb[n] = pack8(k0, k1);       // hold kv as bf16 for the u pass
    }
#pragma unroll
    for (int n = 0; n < 8; ++n) {   // reduce partials across the 8 dim-lanes
      s[n] += __shfl_xor(s[n], 1, 64);
      s[n] += __shfl_xor(s[n], 2, 64);
      s[n] += __shfl_xor(s[n], 4, 64);
    }
    float mx = s[0];
#pragma unroll
    for (int n = 1; n < 8; ++n) mx = fmaxf(mx, s[n]);
    float ev[8];
    float esum = 0.f;
#pragma unroll
    for (int n = 0; n < 8; ++n) { ev[n] = __expf((s[n] - mx) * 0.125f); esum += ev[n]; }
    const float rinv = 1.0f / esum;

    f32x4 u0 = {0.f, 0.f, 0.f, 0.f}, u1 = u0;
#pragma unroll
    for (int n = 0; n < 8; ++n) {
      const float a = ev[n];
      short8 pk = kvb[n];
      u0 += a * (f32x4){bf2f((unsigned short)pk[0]), bf2f((unsigned short)pk[1]),
                        bf2f((unsigned short)pk[2]), bf2f((unsigned short)pk[3])};
      u1 += a * (f32x4){bf2f((unsigned short)pk[4]), bf2f((unsigned short)pk[5]),
                        bf2f((unsigned short)pk[6]), bf2f((unsigned short)pk[7])};
    }
    u0 *= rinv; u1 *= rinv;
    *(short8*)(lds_u + rl * LDU + db) = pack8(u0, u1);
  }
  WAVE_LDS_FENCE();

  // ---- GEMM2: o[16][64] = u @ w_v^T (K=64, 2 k-steps) ----
  f32x4 o4[4];
#pragma unroll
  for (int ct = 0; ct < 4; ++ct) o4[ct] = (f32x4){0.f, 0.f, 0.f, 0.f};
#pragma unroll
  for (int ks = 0; ks < 2; ++ks) {
    short8 ua = *(const short8*)(lds_u + m * LDU + ks * 32 + quad * 8);
#pragma unroll
    for (int ct = 0; ct < 4; ++ct) {
      short8 wf = *(const short8*)(wvb + (ct * 16 + m) * 64 + ks * 32 + quad * 8);
      o4[ct] = __builtin_amdgcn_mfma_f32_16x16x32_bf16(ua, wf, o4[ct], 0, 0, 0);
    }
  }

  // ---- o -> LDS (reuse t tile; all t reads already retired in-order) ----
#pragma unroll
  for (int ct = 0; ct < 4; ++ct)
#pragma unroll
    for (int r = 0; r < 4; ++r)
      lds_t[(quad * 4 + r) * LDT + ct * 16 + m] = o4[ct][r];
  WAVE_LDS_FENCE();

  // ---- LayerNorm over 64 dims (8 lanes/row, 2 passes) + store ----
#pragma unroll
  for (int p = 0; p < 2; ++p) {
    const int rl = p * 8 + rseg;
    const long brow = row0 + rl;
    const float* op = lds_t + rl * LDT + db;
    f32x4 x0 = ((const f32x4*)op)[0];
    f32x4 x1 = ((const f32x4*)op)[1];
    f32x4 sv = x0 + x1;
    f32x4 sq = x0 * x0 + x1 * x1;
    float s1 = sv[0] + sv[1] + sv[2] + sv[3];
    float s2 = sq[0] + sq[1] + sq[2] + sq[3];
    s1 += __shfl_xor(s1, 1, 64); s1 += __shfl_xor(s1, 2, 64); s1 += __shfl_xor(s1, 4, 64);
    s2 += __shfl_xor(s2, 1, 64); s2 += __shfl_xor(s2, 2, 64); s2 += __shfl_xor(s2, 4, 64);
    const float mu   = s1 * 0.015625f;
    const float var  = s2 * 0.015625f - mu * mu;
    const float rstd = rsqrtf(var + 1e-5f);
    float* dst = out + brow * 64 + db;
    ((f32x4*)dst)[0] = (x0 - mu) * rstd * g0 + e0;
    ((f32x4*)dst)[1] = (x1 - mu) * rstd * g1 + e1;
  }
}

extern "C" void kernel_launch(void* const* d_in, const int* in_sizes, int n_in,
                              void* d_out, int out_size, void* d_ws, size_t ws_size,
                              hipStream_t stream) {
  const float* query = (const float*)d_in[0];
  const float* kv    = (const float*)d_in[1];
  const float* w_q   = (const float*)d_in[2];
  const float* w_k   = (const float*)d_in[3];
  const float* w_v   = (const float*)d_in[4];
  const float* gamma = (const float*)d_in[5];
  const float* beta  = (const float*)d_in[6];
  float* out = (float*)d_out;

  unsigned short* mt  = (unsigned short*)d_ws;   // 512*64 bf16
  unsigned short* wvb = mt + QD * KD;            // 64*64 bf16

  const int Bn = in_sizes[0] / QD;               // 65536

  prep_kernel<<<(QD * KD + KD * KD + 255) / 256, 256, 0, stream>>>(w_q, w_k, w_v, mt, wvb);
  fused_kernel<<<Bn / 64, 256, 0, stream>>>(query, kv, mt, wvb, gamma, beta, out);
}

// Round 2
// 302.973 us; speedup vs baseline: 1.0007x; 1.0007x over previous
//
#include <hip/hip_runtime.h>

#define QD 512
#define KD 64
#define LDT 68   // t/o tile row stride in floats (64 + 4 pad); 272 B, 16B-aligned
#define LDU 72   // u tile row stride in shorts (64 + 8 pad); 144 B, 16B-aligned

typedef __attribute__((ext_vector_type(8))) short short8;
typedef __attribute__((ext_vector_type(4))) float f32x4;

static __device__ __forceinline__ unsigned short f2bf(float f) {
  unsigned u = __builtin_bit_cast(unsigned, f);
  u += 0x7FFFu + ((u >> 16) & 1u);   // round-to-nearest-even
  return (unsigned short)(u >> 16);
}
static __device__ __forceinline__ float bf2f(unsigned short s) {
  return __builtin_bit_cast(float, (unsigned)s << 16);
}
static __device__ __forceinline__ short8 pack8(f32x4 a, f32x4 b) {
  short8 r;
  r[0] = (short)f2bf(a[0]); r[1] = (short)f2bf(a[1]);
  r[2] = (short)f2bf(a[2]); r[3] = (short)f2bf(a[3]);
  r[4] = (short)f2bf(b[0]); r[5] = (short)f2bf(b[1]);
  r[6] = (short)f2bf(b[2]); r[7] = (short)f2bf(b[3]);
  return r;
}

// wave-local LDS handoff: drain DS ops; "memory" clobber stops the compiler
// from moving any memory op across. No barriers anywhere in the hot path.
#define WAVE_LDS_FENCE() asm volatile("s_waitcnt lgkmcnt(0)" ::: "memory")

// Prep: M^T[c][d] = sum_e w_q[e,d]*w_k[e,c]  (bf16), plus w_v cast to bf16.
__global__ __launch_bounds__(256) void prep_kernel(
    const float* __restrict__ w_q, const float* __restrict__ w_k,
    const float* __restrict__ w_v, unsigned short* __restrict__ mt,
    unsigned short* __restrict__ wvb) {
  const int tid = (int)(blockIdx.x * 256 + threadIdx.x);
  if (tid < QD * KD) {
    const int c = tid >> 9;      // 0..63
    const int d = tid & 511;     // 0..511
    float acc = 0.f;
#pragma unroll 8
    for (int e = 0; e < 64; ++e)
      acc = fmaf(w_q[e * QD + d], w_k[e * KD + c], acc);
    mt[c * QD + d] = f2bf(acc);
  } else {
    const int i = tid - QD * KD;
    if (i < KD * KD) wvb[i] = f2bf(w_v[i]);
  }
}

// Single-wave blocks (64 threads): each wave owns 16 rows end-to-end.
// Round-1 evidence: the 4-wave packaging quartered the grid (1024 blocks ->
// only 4 blocks/CU of available work, 8 waves/CU resident, 25% occupancy)
// and the kernel is latency-bound (1.9 KB in flight per CU vs ~9 KB needed).
// 1-wave blocks -> 4096 blocks -> 16 blocks/CU available; LDS cap 24, VGPR
// cap 24 -> all resident. This is the parallelism lever, nothing else changed.
__global__ __launch_bounds__(64) void fused_kernel(
    const float* __restrict__ query,
    const float* __restrict__ kv,
    const unsigned short* __restrict__ mt,
    const unsigned short* __restrict__ wvb,
    const float* __restrict__ gamma,
    const float* __restrict__ beta,
    float* __restrict__ out) {
  // per-wave private tiles: t/o 16x68 f32 (4352 B) + u 16x72 bf16 (2304 B)
  __shared__ __align__(16) float lds_t[16 * LDT];
  __shared__ __align__(16) unsigned short lds_u[16 * LDU];

  const int l    = (int)threadIdx.x & 63;
  const int m    = l & 15;
  const int quad = l >> 4;

  const long row0 = (long)blockIdx.x * 16;   // 16 rows per wave

  // ---- GEMM1: t[16][64] = q_tile[16][512] @ M[512][64] ----
  // A-frag: lane reads query[row0+m][ks*32 + quad*8 .. +8] (32 B fp32, HBM).
  // B-frag ct: lane reads mt[(ct*16+m)][ks*32 + quad*8 .. +8] (16 B bf16, L2).
  const float* qbase = query + (row0 + m) * QD + quad * 8;
  const unsigned short* mbase = mt + m * QD + quad * 8;

  f32x4 acc[4];
#pragma unroll
  for (int ct = 0; ct < 4; ++ct) acc[ct] = (f32x4){0.f, 0.f, 0.f, 0.f};

  // depth-2 prefetch on query (HBM latency), depth-1 on M^T (L2 latency)
  f32x4 q0 = ((const f32x4*)qbase)[0];
  f32x4 q1 = ((const f32x4*)qbase)[1];
  f32x4 p0 = ((const f32x4*)(qbase + 32))[0];
  f32x4 p1 = ((const f32x4*)(qbase + 32))[1];
  short8 bc[4], bn[4];
#pragma unroll
  for (int ct = 0; ct < 4; ++ct)
    bc[ct] = *(const short8*)(mbase + ct * 16 * QD);

#pragma unroll
  for (int ks = 0; ks < 16; ++ks) {
    short8 af = pack8(q0, q1);
    if (ks < 15) {
#pragma unroll
      for (int ct = 0; ct < 4; ++ct)
        bn[ct] = *(const short8*)(mbase + ct * 16 * QD + (ks + 1) * 32);
    }
    q0 = p0; q1 = p1;
    if (ks < 14) {
      const float* np = qbase + (ks + 2) * 32;
      p0 = ((const f32x4*)np)[0];
      p1 = ((const f32x4*)np)[1];
    }
#pragma unroll
    for (int ct = 0; ct < 4; ++ct)
      acc[ct] = __builtin_amdgcn_mfma_f32_16x16x32_bf16(af, bc[ct], acc[ct], 0, 0, 0);
#pragma unroll
    for (int ct = 0; ct < 4; ++ct) bc[ct] = bn[ct];   // dead at ks==15, DCE'd
  }

  // ---- t -> LDS (C layout: col = ct*16+m, row = quad*4+r), wave-local ----
#pragma unroll
  for (int ct = 0; ct < 4; ++ct)
#pragma unroll
    for (int r = 0; r < 4; ++r)
      lds_t[(quad * 4 + r) * LDT + ct * 16 + m] = acc[ct][r];
  WAVE_LDS_FENCE();

  // ---- attention: 8 lanes/row, 16 rows in 2 passes of 8 ----
  const int rseg = l >> 3;    // 0..7: row within pass
  const int o8   = l & 7;     // dim segment
  const int db   = o8 * 8;

  // hoist gamma/beta (L2)
  f32x4 g0 = ((const f32x4*)(gamma + db))[0];
  f32x4 g1 = ((const f32x4*)(gamma + db))[1];
  f32x4 e0 = ((const f32x4*)(beta + db))[0];
  f32x4 e1 = ((const f32x4*)(beta + db))[1];

#pragma unroll
  for (int p = 0; p < 2; ++p) {
    const int rl = p * 8 + rseg;
    const long brow = row0 + rl;
    const float* tp = lds_t + rl * LDT + db;
    f32x4 tv0 = ((const f32x4*)tp)[0];
    f32x4 tv1 = ((const f32x4*)tp)[1];

    float s[8];
    short8 kvb[8];
#pragma unroll
    for (int n = 0; n < 8; ++n) {   // 16 independent dwordx4 -> 256 B in flight
      const float* kp = kv + (brow * 8 + n) * 64 + db;
      f32x4 k0 = ((const f32x4*)kp)[0];
      f32x4 k1 = ((const f32x4*)kp)[1];
      f32x4 d = tv0 * k0 + tv1 * k1;
      s[n] = d[0] + d[1] + d[2] + d[3];
      kvb[n] = pack8(k0, k1);       // hold kv as bf16 for the u pass
    }
#pragma unroll
    for (int n = 0; n < 8; ++n) {   // reduce partials across the 8 dim-lanes
      s[n] += __shfl_xor(s[n], 1, 64);
      s[n] += __shfl_xor(s[n], 2, 64);
      s[n] += __shfl_xor(s[n], 4, 64);
    }
    float mx = s[0];
#pragma unroll
    for (int n = 1; n < 8; ++n) mx = fmaxf(mx, s[n]);
    float ev[8];
    float esum = 0.f;
#pragma unroll
    for (int n = 0; n < 8; ++n) { ev[n] = __expf((s[n] - mx) * 0.125f); esum += ev[n]; }
    const float rinv = 1.0f / esum;

    f32x4 u0 = {0.f, 0.f, 0.f, 0.f}, u1 = u0;
#pragma unroll
    for (int n = 0; n < 8; ++n) {
      const float a = ev[n];
      short8 pk = kvb[n];
      u0 += a * (f32x4){bf2f((unsigned short)pk[0]), bf2f((unsigned short)pk[1]),
                        bf2f((unsigned short)pk[2]), bf2f((unsigned short)pk[3])};
      u1 += a * (f32x4){bf2f((unsigned short)pk[4]), bf2f((unsigned short)pk[5]),
                        bf2f((unsigned short)pk[6]), bf2f((unsigned short)pk[7])};
    }
    u0 *= rinv; u1 *= rinv;
    *(short8*)(lds_u + rl * LDU + db) = pack8(u0, u1);
  }
  WAVE_LDS_FENCE();

  // ---- GEMM2: o[16][64] = u @ w_v^T (K=64, 2 k-steps) ----
  f32x4 o4[4];
#pragma unroll
  for (int ct = 0; ct < 4; ++ct) o4[ct] = (f32x4){0.f, 0.f, 0.f, 0.f};
#pragma unroll
  for (int ks = 0; ks < 2; ++ks) {
    short8 ua = *(const short8*)(lds_u + m * LDU + ks * 32 + quad * 8);
#pragma unroll
    for (int ct = 0; ct < 4; ++ct) {
      short8 wf = *(const short8*)(wvb + (ct * 16 + m) * 64 + ks * 32 + quad * 8);
      o4[ct] = __builtin_amdgcn_mfma_f32_16x16x32_bf16(ua, wf, o4[ct], 0, 0, 0);
    }
  }

  // ---- o -> LDS (reuse t tile; all t reads already retired in-order) ----
#pragma unroll
  for (int ct = 0; ct < 4; ++ct)
#pragma unroll
    for (int r = 0; r < 4; ++r)
      lds_t[(quad * 4 + r) * LDT + ct * 16 + m] = o4[ct][r];
  WAVE_LDS_FENCE();

  // ---- LayerNorm over 64 dims (8 lanes/row, 2 passes) + store ----
#pragma unroll
  for (int p = 0; p < 2; ++p) {
    const int rl = p * 8 + rseg;
    const long brow = row0 + rl;
    const float* op = lds_t + rl * LDT + db;
    f32x4 x0 = ((const f32x4*)op)[0];
    f32x4 x1 = ((const f32x4*)op)[1];
    f32x4 sv = x0 + x1;
    f32x4 sq = x0 * x0 + x1 * x1;
    float s1 = sv[0] + sv[1] + sv[2] + sv[3];
    float s2 = sq[0] + sq[1] + sq[2] + sq[3];
    s1 += __shfl_xor(s1, 1, 64); s1 += __shfl_xor(s1, 2, 64); s1 += __shfl_xor(s1, 4, 64);
    s2 += __shfl_xor(s2, 1, 64); s2 += __shfl_xor(s2, 2, 64); s2 += __shfl_xor(s2, 4, 64);
    const float mu   = s1 * 0.015625f;
    const float var  = s2 * 0.015625f - mu * mu;
    const float rstd = rsqrtf(var + 1e-5f);
    float* dst = out + brow * 64 + db;
    ((f32x4*)dst)[0] = (x0 - mu) * rstd * g0 + e0;
    ((f32x4*)dst)[1] = (x1 - mu) * rstd * g1 + e1;
  }
}

extern "C" void kernel_launch(void* const* d_in, const int* in_sizes, int n_in,
                              void* d_out, int out_size, void* d_ws, size_t ws_size,
                              hipStream_t stream) {
  const float* query = (const float*)d_in[0];
  const float* kv    = (const float*)d_in[1];
  const float* w_q   = (const float*)d_in[2];
  const float* w_k   = (const float*)d_in[3];
  const float* w_v   = (const float*)d_in[4];
  const float* gamma = (const float*)d_in[5];
  const float* beta  = (const float*)d_in[6];
  float* out = (float*)d_out;

  unsigned short* mt  = (unsigned short*)d_ws;   // 512*64 bf16
  unsigned short* wvb = mt + QD * KD;            // 64*64 bf16

  const int Bn = in_sizes[0] / QD;               // 65536

  prep_kernel<<<(QD * KD + KD * KD + 255) / 256, 256, 0, stream>>>(w_q, w_k, w_v, mt, wvb);
  fused_kernel<<<Bn / 16, 64, 0, stream>>>(query, kv, mt, wvb, gamma, beta, out);
}

// Round 3
// 300.998 us; speedup vs baseline: 1.0072x; 1.0066x over previous
//
#include <hip/hip_runtime.h>

#define QD 512
#define KD 64
#define LDT 68   // t/o tile row stride in floats (64 + 4 pad); 272 B, 16B-aligned
#define LDU 72   // u tile row stride in shorts (64 + 8 pad); 144 B, 16B-aligned

typedef __attribute__((ext_vector_type(8))) short short8;
typedef __attribute__((ext_vector_type(4))) float f32x4;

static __device__ __forceinline__ unsigned short f2bf(float f) {
  unsigned u = __builtin_bit_cast(unsigned, f);
  u += 0x7FFFu + ((u >> 16) & 1u);   // round-to-nearest-even
  return (unsigned short)(u >> 16);
}
static __device__ __forceinline__ float bf2f(unsigned short s) {
  return __builtin_bit_cast(float, (unsigned)s << 16);
}
static __device__ __forceinline__ short8 pack8(f32x4 a, f32x4 b) {
  short8 r;
  r[0] = (short)f2bf(a[0]); r[1] = (short)f2bf(a[1]);
  r[2] = (short)f2bf(a[2]); r[3] = (short)f2bf(a[3]);
  r[4] = (short)f2bf(b[0]); r[5] = (short)f2bf(b[1]);
  r[6] = (short)f2bf(b[2]); r[7] = (short)f2bf(b[3]);
  return r;
}

// wave-local LDS handoff: drain DS ops; "memory" clobber stops the compiler
// from moving any memory op across. No barriers anywhere in the hot path.
#define WAVE_LDS_FENCE() asm volatile("s_waitcnt lgkmcnt(0)" ::: "memory")

// Prep: M^T[c][d] = sum_e w_q[e,d]*w_k[e,c]  (bf16), plus w_v cast to bf16.
__global__ __launch_bounds__(256) void prep_kernel(
    const float* __restrict__ w_q, const float* __restrict__ w_k,
    const float* __restrict__ w_v, unsigned short* __restrict__ mt,
    unsigned short* __restrict__ wvb) {
  const int tid = (int)(blockIdx.x * 256 + threadIdx.x);
  if (tid < QD * KD) {
    const int c = tid >> 9;      // 0..63
    const int d = tid & 511;     // 0..511
    float acc = 0.f;
#pragma unroll 8
    for (int e = 0; e < 64; ++e)
      acc = fmaf(w_q[e * QD + d], w_k[e * KD + c], acc);
    mt[c * QD + d] = f2bf(acc);
  } else {
    const int i = tid - QD * KD;
    if (i < KD * KD) wvb[i] = f2bf(w_v[i]);
  }
}

// Single-wave blocks, 16 rows/wave. Round-2 evidence: packaging/availability
// is NOT the limiter (1024x4w and 4096x1w identical at 114 us, 25% occ).
// Little's law says ~0.25 KB in flight per wave (waves ~90% stalled with zero
// loads outstanding). This version buys memory-level parallelism with VGPRs:
//  - all pass-0 kv loads issued at kernel ENTRY (hide under GEMM1)
//  - all pass-1 kv loads issued right after the t-transpose (hide under pass-0)
//  - GEMM1 q prefetch ring depth-4, mt depth-2
// NOTE: no min-waves clause on __launch_bounds__ (earlier evidence: (256,6)
// collapsed the allocator to 40 VGPRs and spilled ~40 MB to scratch).
__global__ __launch_bounds__(64) void fused_kernel(
    const float* __restrict__ query,
    const float* __restrict__ kv,
    const unsigned short* __restrict__ mt,
    const unsigned short* __restrict__ wvb,
    const float* __restrict__ gamma,
    const float* __restrict__ beta,
    float* __restrict__ out) {
  // per-wave private tiles: t/o 16x68 f32 (4352 B) + u 16x72 bf16 (2304 B)
  __shared__ __align__(16) float lds_t[16 * LDT];
  __shared__ __align__(16) unsigned short lds_u[16 * LDU];

  const int l    = (int)threadIdx.x & 63;
  const int m    = l & 15;
  const int quad = l >> 4;

  const long row0 = (long)blockIdx.x * 16;   // 16 rows per wave

  // ---- issue ALL pass-0 kv loads NOW (16 dwordx4/lane-group in flight) ----
  const int rseg = l >> 3;    // 0..7: row within pass
  const int o8   = l & 7;     // dim segment
  const int db   = o8 * 8;
  const float* kbase0 = kv + ((row0 + rseg) * 8) * 64 + db;
  f32x4 kva[8][2];
#pragma unroll
  for (int n = 0; n < 8; ++n) {
    kva[n][0] = ((const f32x4*)(kbase0 + n * 64))[0];
    kva[n][1] = ((const f32x4*)(kbase0 + n * 64))[1];
  }

  // ---- GEMM1: t[16][64] = q_tile[16][512] @ M[512][64] ----
  // A-frag: lane reads query[row0+m][ks*32 + quad*8 .. +8] (32 B fp32, HBM).
  // B-frag ct: lane reads mt[(ct*16+m)][ks*32 + quad*8 .. +8] (16 B bf16, L2).
  const float* qbase = query + (row0 + m) * QD + quad * 8;
  const unsigned short* mbase = mt + m * QD + quad * 8;

  f32x4 acc[4];
#pragma unroll
  for (int ct = 0; ct < 4; ++ct) acc[ct] = (f32x4){0.f, 0.f, 0.f, 0.f};

  // depth-4 ring on query (HBM), depth-2 on M^T (L2)
  f32x4 qr[4][2];
#pragma unroll
  for (int d = 0; d < 4; ++d) {
    qr[d][0] = ((const f32x4*)(qbase + d * 32))[0];
    qr[d][1] = ((const f32x4*)(qbase + d * 32))[1];
  }
  short8 bb[2][4];
#pragma unroll
  for (int ct = 0; ct < 4; ++ct) {
    bb[0][ct] = *(const short8*)(mbase + ct * 16 * QD);
    bb[1][ct] = *(const short8*)(mbase + ct * 16 * QD + 32);
  }

#pragma unroll
  for (int ks = 0; ks < 16; ++ks) {
    const int slot = ks & 3, bs = ks & 1;
    short8 af = pack8(qr[slot][0], qr[slot][1]);
    if (ks < 12) {   // refill q ring with k-step ks+4
      const float* np = qbase + (ks + 4) * 32;
      qr[slot][0] = ((const f32x4*)np)[0];
      qr[slot][1] = ((const f32x4*)np)[1];
    }
#pragma unroll
    for (int ct = 0; ct < 4; ++ct)
      acc[ct] = __builtin_amdgcn_mfma_f32_16x16x32_bf16(af, bb[bs][ct], acc[ct], 0, 0, 0);
    if (ks < 14) {   // refill mt ring with k-step ks+2
#pragma unroll
      for (int ct = 0; ct < 4; ++ct)
        bb[bs][ct] = *(const short8*)(mbase + ct * 16 * QD + (ks + 2) * 32);
    }
  }

  // ---- t -> LDS (C layout: col = ct*16+m, row = quad*4+r), wave-local ----
#pragma unroll
  for (int ct = 0; ct < 4; ++ct)
#pragma unroll
    for (int r = 0; r < 4; ++r)
      lds_t[(quad * 4 + r) * LDT + ct * 16 + m] = acc[ct][r];
  WAVE_LDS_FENCE();

  // ---- issue ALL pass-1 kv loads (hide under pass-0 compute) ----
  const float* kbase1 = kv + ((row0 + 8 + rseg) * 8) * 64 + db;
  f32x4 kvc[8][2];
#pragma unroll
  for (int n = 0; n < 8; ++n) {
    kvc[n][0] = ((const f32x4*)(kbase1 + n * 64))[0];
    kvc[n][1] = ((const f32x4*)(kbase1 + n * 64))[1];
  }

  // ---- attention pass (8 lanes/row), data already in registers ----
  auto attn_pass = [&](const f32x4 (&kvv)[8][2], int rl) {
    const float* tp = lds_t + rl * LDT + db;
    f32x4 tv0 = ((const f32x4*)tp)[0];
    f32x4 tv1 = ((const f32x4*)tp)[1];

    float s[8];
    short8 pk[8];
#pragma unroll
    for (int n = 0; n < 8; ++n) {
      f32x4 k0 = kvv[n][0];
      f32x4 k1 = kvv[n][1];
      f32x4 d = tv0 * k0 + tv1 * k1;
      s[n] = d[0] + d[1] + d[2] + d[3];
      pk[n] = pack8(k0, k1);          // hold kv as bf16 for the u pass
    }
#pragma unroll
    for (int n = 0; n < 8; ++n) {     // reduce partials across the 8 dim-lanes
      s[n] += __shfl_xor(s[n], 1, 64);
      s[n] += __shfl_xor(s[n], 2, 64);
      s[n] += __shfl_xor(s[n], 4, 64);
    }
    float mx = s[0];
#pragma unroll
    for (int n = 1; n < 8; ++n) mx = fmaxf(mx, s[n]);
    float ev[8];
    float esum = 0.f;
#pragma unroll
    for (int n = 0; n < 8; ++n) { ev[n] = __expf((s[n] - mx) * 0.125f); esum += ev[n]; }
    const float rinv = 1.0f / esum;

    f32x4 u0 = {0.f, 0.f, 0.f, 0.f}, u1 = u0;
#pragma unroll
    for (int n = 0; n < 8; ++n) {
      const float a = ev[n];
      short8 p = pk[n];
      u0 += a * (f32x4){bf2f((unsigned short)p[0]), bf2f((unsigned short)p[1]),
                        bf2f((unsigned short)p[2]), bf2f((unsigned short)p[3])};
      u1 += a * (f32x4){bf2f((unsigned short)p[4]), bf2f((unsigned short)p[5]),
                        bf2f((unsigned short)p[6]), bf2f((unsigned short)p[7])};
    }
    u0 *= rinv; u1 *= rinv;
    *(short8*)(lds_u + rl * LDU + db) = pack8(u0, u1);
  };

  attn_pass(kva, rseg);        // rows 0..7
  attn_pass(kvc, 8 + rseg);    // rows 8..15
  WAVE_LDS_FENCE();

  // ---- GEMM2: o[16][64] = u @ w_v^T (K=64, 2 k-steps) ----
  f32x4 o4[4];
#pragma unroll
  for (int ct = 0; ct < 4; ++ct) o4[ct] = (f32x4){0.f, 0.f, 0.f, 0.f};
#pragma unroll
  for (int ks = 0; ks < 2; ++ks) {
    short8 ua = *(const short8*)(lds_u + m * LDU + ks * 32 + quad * 8);
#pragma unroll
    for (int ct = 0; ct < 4; ++ct) {
      short8 wf = *(const short8*)(wvb + (ct * 16 + m) * 64 + ks * 32 + quad * 8);
      o4[ct] = __builtin_amdgcn_mfma_f32_16x16x32_bf16(ua, wf, o4[ct], 0, 0, 0);
    }
  }

  // ---- o -> LDS (reuse t tile; all t reads already retired in-order) ----
#pragma unroll
  for (int ct = 0; ct < 4; ++ct)
#pragma unroll
    for (int r = 0; r < 4; ++r)
      lds_t[(quad * 4 + r) * LDT + ct * 16 + m] = o4[ct][r];
  WAVE_LDS_FENCE();

  // ---- LayerNorm over 64 dims (8 lanes/row, 2 passes) + store ----
  // gamma/beta loaded here (L2-hot, once per wave) to keep peak VGPR down
  f32x4 g0 = ((const f32x4*)(gamma + db))[0];
  f32x4 g1 = ((const f32x4*)(gamma + db))[1];
  f32x4 e0 = ((const f32x4*)(beta + db))[0];
  f32x4 e1 = ((const f32x4*)(beta + db))[1];
#pragma unroll
  for (int p = 0; p < 2; ++p) {
    const int rl = p * 8 + rseg;
    const long brow = row0 + rl;
    const float* op = lds_t + rl * LDT + db;
    f32x4 x0 = ((const f32x4*)op)[0];
    f32x4 x1 = ((const f32x4*)op)[1];
    f32x4 sv = x0 + x1;
    f32x4 sq = x0 * x0 + x1 * x1;
    float s1 = sv[0] + sv[1] + sv[2] + sv[3];
    float s2 = sq[0] + sq[1] + sq[2] + sq[3];
    s1 += __shfl_xor(s1, 1, 64); s1 += __shfl_xor(s1, 2, 64); s1 += __shfl_xor(s1, 4, 64);
    s2 += __shfl_xor(s2, 1, 64); s2 += __shfl_xor(s2, 2, 64); s2 += __shfl_xor(s2, 4, 64);
    const float mu   = s1 * 0.015625f;
    const float var  = s2 * 0.015625f - mu * mu;
    const float rstd = rsqrtf(var + 1e-5f);
    float* dst = out + brow * 64 + db;
    ((f32x4*)dst)[0] = (x0 - mu) * rstd * g0 + e0;
    ((f32x4*)dst)[1] = (x1 - mu) * rstd * g1 + e1;
  }
}

extern "C" void kernel_launch(void* const* d_in, const int* in_sizes, int n_in,
                              void* d_out, int out_size, void* d_ws, size_t ws_size,
                              hipStream_t stream) {
  const float* query = (const float*)d_in[0];
  const float* kv    = (const float*)d_in[1];
  const float* w_q   = (const float*)d_in[2];
  const float* w_k   = (const float*)d_in[3];
  const float* w_v   = (const float*)d_in[4];
  const float* gamma = (const float*)d_in[5];
  const float* beta  = (const float*)d_in[6];
  float* out = (float*)d_out;

  unsigned short* mt  = (unsigned short*)d_ws;   // 512*64 bf16
  unsigned short* wvb = mt + QD * KD;            // 64*64 bf16

  const int Bn = in_sizes[0] / QD;               // 65536

  prep_kernel<<<(QD * KD + KD * KD + 255) / 256, 256, 0, stream>>>(w_q, w_k, w_v, mt, wvb);
  fused_kernel<<<Bn / 16, 64, 0, stream>>>(query, kv, mt, wvb, gamma, beta, out);
}

// Round 4
// 293.354 us; speedup vs baseline: 1.0335x; 1.0261x over previous
//
#include <hip/hip_runtime.h>

#define QD 512
#define KD 64
#define NR 32    // rows per block (4 waves x 16-col tiles, 2 row-tiles)
#define LDT 68   // t/o tile row stride in floats (64 + 4 pad)
#define LDU 72   // u tile row stride in shorts (64 + 8 pad)

typedef __attribute__((ext_vector_type(8))) short short8;
typedef __attribute__((ext_vector_type(4))) float f32x4;

static __device__ __forceinline__ unsigned short f2bf(float f) {
  unsigned u = __builtin_bit_cast(unsigned, f);
  u += 0x7FFFu + ((u >> 16) & 1u);   // round-to-nearest-even
  return (unsigned short)(u >> 16);
}
static __device__ __forceinline__ float bf2f(unsigned short s) {
  return __builtin_bit_cast(float, (unsigned)s << 16);
}
static __device__ __forceinline__ short8 pack8(f32x4 a, f32x4 b) {
  short8 r;
  r[0] = (short)f2bf(a[0]); r[1] = (short)f2bf(a[1]);
  r[2] = (short)f2bf(a[2]); r[3] = (short)f2bf(a[3]);
  r[4] = (short)f2bf(b[0]); r[5] = (short)f2bf(b[1]);
  r[6] = (short)f2bf(b[2]); r[7] = (short)f2bf(b[3]);
  return r;
}

// async global->LDS DMA, 16B per lane; LDS dest = wave-uniform base + lane*16.
// In-flight bytes live in the memory system, not VGPRs -> compiler can't sink it.
static __device__ __forceinline__ void dma16(const void* g, void* l) {
  __builtin_amdgcn_global_load_lds(
      (const __attribute__((address_space(1))) void*)g,
      (__attribute__((address_space(3))) void*)l, 16, 0, 0);
}

// Prep: M^T[c][d] = sum_e w_q[e,d]*w_k[e,c]  (bf16), plus w_v cast to bf16.
__global__ __launch_bounds__(256) void prep_kernel(
    const float* __restrict__ w_q, const float* __restrict__ w_k,
    const float* __restrict__ w_v, unsigned short* __restrict__ mt,
    unsigned short* __restrict__ wvb) {
  const int tid = (int)(blockIdx.x * 256 + threadIdx.x);
  if (tid < QD * KD) {
    const int c = tid >> 9;      // 0..63
    const int d = tid & 511;     // 0..511
    float acc = 0.f;
#pragma unroll 8
    for (int e = 0; e < 64; ++e)
      acc = fmaf(w_q[e * QD + d], w_k[e * KD + c], acc);
    mt[c * QD + d] = f2bf(acc);
  } else {
    const int i = tid - QD * KD;
    if (i < KD * KD) wvb[i] = f2bf(w_v[i]);
  }
}

// R0 structure (4-wave block, 32 rows, best measured) + async DMA staging:
// GEMM1 streams query AND mt via global_load_lds (double-buffered 32-dim
// chunks, counted vmcnt(2), 2 barriers/chunk). The DMA queue holds the
// in-flight HBM bytes (2 chunks x 8KB x ~8 blk/CU ~ 64KB/CU) -- register
// count no longer limits memory-level parallelism, and the compiler cannot
// sink side-effecting DMA intrinsics (R1-R3 evidence: it sank every
// reg-based prefetch). Bank conflicts on fragment reads are fixed by
// pre-swizzling the DMA *source* addresses (LDS dest is linear-forced).
__global__ __launch_bounds__(256) void fused_kernel(
    const float* __restrict__ query,
    const float* __restrict__ kv,
    const unsigned short* __restrict__ mt,
    const unsigned short* __restrict__ wvb,
    const float* __restrict__ gamma,
    const float* __restrict__ beta,
    float* __restrict__ out) {
  // regionA: q-stage dbuf (2x4096) -> aliased by t/o tile (32*68*4 = 8704)
  // regionB: mt-stage dbuf (2x4096) -> aliased by u tile (32*72*2 = 4608)
  __shared__ __align__(16) char regionA[NR * LDT * 4];   // 8704 B
  __shared__ __align__(16) char regionB[8192];           // 8192 B
  float* lds_t = (float*)regionA;
  unsigned short* lds_u = (unsigned short*)regionB;

  const int tid  = (int)threadIdx.x;
  const int w    = tid >> 6;       // wave 0..3 -> col-tile of 16
  const int l    = tid & 63;
  const int m    = l & 15;
  const int quad = l >> 4;
  const long row0 = (long)blockIdx.x * NR;

  // ---- DMA source lane addresses (pre-swizzled for conflict-free reads) ----
  // q granule: row r = w*8 + (l>>3) within block, true k-oct = (l&7)^(r&7)
  const float* qsrc = query + (row0 + w * 8 + (l >> 3)) * QD
                            + (((l & 7) ^ ((l >> 3) & 7)) * 4);
  // mt granule: row r = w*16 + (l>>2), true k-oct(16B) = (l&3)^((r>>2)&3)
  const unsigned short* msrc = mt + (w * 16 + (l >> 2)) * QD
                                  + (((l & 3) ^ ((l >> 4) & 3)) * 8);
  char* qdst = regionA + w * 1024;   // + (c&1)*4096
  char* mdst = regionB + w * 1024;

  // prologue: chunks 0,1 in flight (2 instrs/chunk/wave -> static vmcnt count)
  dma16(qsrc, qdst);            dma16(msrc, mdst);
  dma16(qsrc + 32, qdst + 4096); dma16(msrc + 32, mdst + 4096);

  // read-side lane byte offsets (swizzled to balanced bank classes)
  const int a0off = m * 128 + (((2 * quad)     ^ (m & 7)) * 16);
  const int a1off = m * 128 + (((2 * quad + 1) ^ (m & 7)) * 16);
  const int boff  = (w * 16 + m) * 64 + ((quad ^ (m >> 2)) * 16);

  f32x4 acc[2];
  acc[0] = (f32x4){0.f, 0.f, 0.f, 0.f};
  acc[1] = (f32x4){0.f, 0.f, 0.f, 0.f};

  // ---- GEMM1: t = q_tile[32][512] @ M[512][64], 16 chunks of K=32 ----
#pragma unroll
  for (int c = 0; c < 16; ++c) {
    // chunk c landed <=> at most 2 of my newer DMA instrs outstanding.
    // vmcnt drains oldest-first (FIFO), so compiler-injected vmem between
    // my instrs only makes this MORE conservative, never unsafe.
    if (c < 15) { asm volatile("s_waitcnt vmcnt(2)" ::: "memory"); }
    else        { asm volatile("s_waitcnt vmcnt(0)" ::: "memory"); }
    __syncthreads();   // all waves' chunk-c DMA confirmed -> LDS consistent

    const char* qb = regionA + (c & 1) * 4096;
    const char* bbuf = regionB + (c & 1) * 4096;
    short8 bf = *(const short8*)(bbuf + boff);
#pragma unroll
    for (int rt = 0; rt < 2; ++rt) {
      f32x4 g0 = *(const f32x4*)(qb + rt * 2048 + a0off);
      f32x4 g1 = *(const f32x4*)(qb + rt * 2048 + a1off);
      short8 af = pack8(g0, g1);
      acc[rt] = __builtin_amdgcn_mfma_f32_16x16x32_bf16(af, bf, acc[rt], 0, 0, 0);
    }
    __syncthreads();   // all waves consumed chunk c -> safe to overwrite buf
    if (c + 2 < 16) {
      dma16(qsrc + (c + 2) * 32, qdst + (c & 1) * 4096);
      dma16(msrc + (c + 2) * 32, mdst + (c & 1) * 4096);
    }
  }

  // ---- write t to LDS (C layout: col=lane&15, row=quad*4+reg) ----
  // Safe to alias q-stage: final chunk's trailing barrier has passed.
#pragma unroll
  for (int rt = 0; rt < 2; ++rt)
#pragma unroll
    for (int r2 = 0; r2 < 4; ++r2)
      lds_t[(rt * 16 + quad * 4 + r2) * LDT + w * 16 + m] = acc[rt][r2];
  __syncthreads();

  // ---- per-row attention: 8 threads per row, 8 dims per thread ----
  const int rl = w * 8 + (l >> 3);   // row 0..31
  const int o8 = l & 7;              // dim segment
  const int db = o8 * 8;             // dim base
  const long brow = row0 + rl;

  const float* tp = lds_t + rl * LDT + db;
  f32x4 tv0 = ((const f32x4*)tp)[0];
  f32x4 tv1 = ((const f32x4*)tp)[1];

  float s[8];
  short8 kvb[8];
#pragma unroll
  for (int n = 0; n < 8; ++n) {
    const float* kp = kv + (brow * 8 + n) * 64 + db;
    f32x4 k0 = ((const f32x4*)kp)[0];
    f32x4 k1 = ((const f32x4*)kp)[1];
    f32x4 d = tv0 * k0 + tv1 * k1;
    s[n] = d[0] + d[1] + d[2] + d[3];
    kvb[n] = pack8(k0, k1);           // hold kv as bf16 for the u pass
  }
#pragma unroll
  for (int n = 0; n < 8; ++n) {       // reduce partials across the 8 dim-lanes
    s[n] += __shfl_xor(s[n], 1, 64);
    s[n] += __shfl_xor(s[n], 2, 64);
    s[n] += __shfl_xor(s[n], 4, 64);
  }
  float mx = s[0];
#pragma unroll
  for (int n = 1; n < 8; ++n) mx = fmaxf(mx, s[n]);
  float ev[8];
  float esum = 0.f;
#pragma unroll
  for (int n = 0; n < 8; ++n) { ev[n] = __expf((s[n] - mx) * 0.125f); esum += ev[n]; }
  const float rinv = 1.0f / esum;

  f32x4 u0 = {0.f, 0.f, 0.f, 0.f}, u1 = u0;
#pragma unroll
  for (int n = 0; n < 8; ++n) {
    const float a = ev[n];
    short8 p = kvb[n];
    u0 += a * (f32x4){bf2f((unsigned short)p[0]), bf2f((unsigned short)p[1]),
                      bf2f((unsigned short)p[2]), bf2f((unsigned short)p[3])};
    u1 += a * (f32x4){bf2f((unsigned short)p[4]), bf2f((unsigned short)p[5]),
                      bf2f((unsigned short)p[6]), bf2f((unsigned short)p[7])};
  }
  u0 *= rinv; u1 *= rinv;
  // u tile aliases mt-stage: all mt reads retired before the last GEMM1 barrier
  *(short8*)(lds_u + rl * LDU + db) = pack8(u0, u1);
  __syncthreads();

  // ---- GEMM2: o = u @ w_v^T (K=64, 2 MFMA k-steps) ----
  short8 wvf0 = *(const short8*)(wvb + (w * 16 + m) * 64 + quad * 8);
  short8 wvf1 = *(const short8*)(wvb + (w * 16 + m) * 64 + 32 + quad * 8);
  f32x4 o[2];
  o[0] = (f32x4){0.f, 0.f, 0.f, 0.f};
  o[1] = (f32x4){0.f, 0.f, 0.f, 0.f};
#pragma unroll
  for (int rt = 0; rt < 2; ++rt) {
    short8 a0 = *(const short8*)(lds_u + (rt * 16 + m) * LDU + quad * 8);
    o[rt] = __builtin_amdgcn_mfma_f32_16x16x32_bf16(a0, wvf0, o[rt], 0, 0, 0);
    short8 a1 = *(const short8*)(lds_u + (rt * 16 + m) * LDU + 32 + quad * 8);
    o[rt] = __builtin_amdgcn_mfma_f32_16x16x32_bf16(a1, wvf1, o[rt], 0, 0, 0);
  }
  // write o into lds_t (safe: all tv reads completed before the u barrier)
#pragma unroll
  for (int rt = 0; rt < 2; ++rt)
#pragma unroll
    for (int r2 = 0; r2 < 4; ++r2)
      lds_t[(rt * 16 + quad * 4 + r2) * LDT + w * 16 + m] = o[rt][r2];
  __syncthreads();

  // ---- LayerNorm over 64 dims (8 lanes per row) ----
  const float* op = lds_t + rl * LDT + db;
  f32x4 x0 = ((const f32x4*)op)[0];
  f32x4 x1 = ((const f32x4*)op)[1];
  f32x4 sv = x0 + x1;
  f32x4 sq = x0 * x0 + x1 * x1;
  float s1 = sv[0] + sv[1] + sv[2] + sv[3];
  float s2 = sq[0] + sq[1] + sq[2] + sq[3];
  s1 += __shfl_xor(s1, 1, 64); s1 += __shfl_xor(s1, 2, 64); s1 += __shfl_xor(s1, 4, 64);
  s2 += __shfl_xor(s2, 1, 64); s2 += __shfl_xor(s2, 2, 64); s2 += __shfl_xor(s2, 4, 64);
  const float mu   = s1 * 0.015625f;
  const float var  = s2 * 0.015625f - mu * mu;
  const float rstd = rsqrtf(var + 1e-5f);
  const float* gp = gamma + db;
  const float* bp = beta + db;
  float* dst = out + brow * 64 + db;
  {
    f32x4 g0 = ((const f32x4*)gp)[0], g1 = ((const f32x4*)gp)[1];
    f32x4 e0 = ((const f32x4*)bp)[0], e1 = ((const f32x4*)bp)[1];
    ((f32x4*)dst)[0] = (x0 - mu) * rstd * g0 + e0;
    ((f32x4*)dst)[1] = (x1 - mu) * rstd * g1 + e1;
  }
}

extern "C" void kernel_launch(void* const* d_in, const int* in_sizes, int n_in,
                              void* d_out, int out_size, void* d_ws, size_t ws_size,
                              hipStream_t stream) {
  const float* query = (const float*)d_in[0];
  const float* kv    = (const float*)d_in[1];
  const float* w_q   = (const float*)d_in[2];
  const float* w_k   = (const float*)d_in[3];
  const float* w_v   = (const float*)d_in[4];
  const float* gamma = (const float*)d_in[5];
  const float* beta  = (const float*)d_in[6];
  float* out = (float*)d_out;

  unsigned short* mt  = (unsigned short*)d_ws;   // 512*64 bf16
  unsigned short* wvb = mt + QD * KD;            // 64*64 bf16

  const int Bn = in_sizes[0] / QD;               // 65536

  prep_kernel<<<(QD * KD + KD * KD + 255) / 256, 256, 0, stream>>>(w_q, w_k, w_v, mt, wvb);
  fused_kernel<<<Bn / NR, 256, 0, stream>>>(query, kv, mt, wvb, gamma, beta, out);
}